// Round 11
// baseline (3970.610 us; speedup 1.0000x reference)
//
#include <hip/hip_runtime.h>
#include <hip/hip_bf16.h>
#include <stdint.h>

// ---------------------------------------------------------------------------
// ConvLSTM (GRU-style) T=512 B=64 D=1024 H=1024.
// xall = X @ [Wzx;Wrx;Wcx]^T (parallel GEMM, bf16), then cooperative DATAFLOW
// recurrent kernel (R5 body + R11 vmcnt hygiene): 64 WGs x 16 cols, per-WG
// monotone flags, double-buffered h/rh in MFMA-fragment-major layout
//   E[kb = col/8][row 0..63][8 bf16]   (16B per (kb,row))
// R11: (i) publish flag store from wave1 (tid==64) so the polling wave0 has
// an empty vmem queue; (ii) WAITV(0) at loop-tail so the next poll starts
// with zero outstanding vmem (polls compile to load+vmcnt(0), per-wave).
// ---------------------------------------------------------------------------

typedef float  f32x4  __attribute__((ext_vector_type(4)));
typedef int    i32x4  __attribute__((ext_vector_type(4)));
typedef __bf16 bf16x8 __attribute__((ext_vector_type(8)));

#define NWG 64
#define TSTEPS 512

// ws layout (bytes)
#define XALL_OFF 0UL
#define XALL_BYTES (32768UL * 3072UL * 2UL)            // 201326592
#define WXP_OFF   (XALL_OFF + XALL_BYTES)
#define WXP_BYTES (3072UL * 1024UL * 2UL)              // 6291456
#define HBUF_OFF  (WXP_OFF + WXP_BYTES)                // 2 x 131072
#define RHBUF_OFF (HBUF_OFF + 262144UL)                // 2 x 131072
#define FLAG_OFF  (RHBUF_OFF + 262144UL)               // flagh 4KB, flagr 4KB
#define WS_NEED   (FLAG_OFF + 8192UL)

#define GL_LDS16(g, l) __builtin_amdgcn_global_load_lds( \
    (const __attribute__((address_space(1))) void*)(const void*)(g), \
    (__attribute__((address_space(3))) void*)(void*)(l), 16, 0, 0)

// coherent 16B load / store (bypass stale L1/L2, coalescable at LLC)
#define ASM_LD16(dst, p) \
  asm volatile("global_load_dwordx4 %0, %1, off sc0 sc1" \
               : "=&v"(dst) : "v"(p) : "memory")
#define ASM_ST16(p, v) \
  asm volatile("global_store_dwordx4 %0, %1, off sc0 sc1" \
               :: "v"(p), "v"(v) : "memory")
#define WAITV(N) do { asm volatile("s_waitcnt vmcnt(" #N ")" ::: "memory"); \
                      __builtin_amdgcn_sched_barrier(0); } while (0)

__device__ __forceinline__ unsigned short f2bf(float f) {
  __hip_bfloat16 h = __float2bfloat16(f);
  return __builtin_bit_cast(unsigned short, h);
}
__device__ __forceinline__ bf16x8 ld16(const void* p) {
  return __builtin_bit_cast(bf16x8, *(const uint4*)p);
}
__device__ __forceinline__ i32x4 ldi4(const void* p) {
  return __builtin_bit_cast(i32x4, *(const uint4*)p);
}
__device__ __forceinline__ f32x4 mfma16(bf16x8 a, bf16x8 b, f32x4 c) {
  return __builtin_amdgcn_mfma_f32_16x16x32_bf16(a, b, c, 0, 0, 0);
}
__device__ __forceinline__ float sigm(float x) {
  return __builtin_amdgcn_rcpf(1.0f + __builtin_amdgcn_exp2f(-1.4426950408889634f * x));
}
__device__ __forceinline__ float tanh_fast(float x) {
  return 1.0f - 2.0f * __builtin_amdgcn_rcpf(1.0f + __builtin_amdgcn_exp2f(2.8853900817779268f * x));
}

// --------------------------- prep kernels ----------------------------------
__global__ void cvt_x(const float* __restrict__ x, __hip_bfloat16* __restrict__ o) {
  size_t i = ((size_t)blockIdx.x * 256 + threadIdx.x) * 4;
  float4 v = *(const float4*)(x + i);
  ushort4 u; u.x = f2bf(v.x); u.y = f2bf(v.y); u.z = f2bf(v.z); u.w = f2bf(v.w);
  *(ushort4*)(o + i) = u;
}

__global__ void pack_w(const float* __restrict__ Wfc, const float* __restrict__ Wfc2,
                       __hip_bfloat16* __restrict__ Wxp) {
  int row = blockIdx.x;
  int k = threadIdx.x * 4;
  const float* src = (row < 2048) ? (Wfc + (size_t)row * 2048 + k)
                                  : (Wfc2 + (size_t)(row - 2048) * 2048 + k);
  float4 v = *(const float4*)src;
  ushort4 u; u.x = f2bf(v.x); u.y = f2bf(v.y); u.z = f2bf(v.z); u.w = f2bf(v.w);
  *(ushort4*)(Wxp + (size_t)row * 1024 + k) = u;
}

__global__ void init_k(__hip_bfloat16* __restrict__ hbuf,
                       int* __restrict__ flagh, int* __restrict__ flagr) {
  size_t i = ((size_t)blockIdx.x * 256 + threadIdx.x) * 4;
  unsigned short hv = f2bf(1e-9f);
  ushort4 u; u.x = hv; u.y = hv; u.z = hv; u.w = hv;
  *(ushort4*)(hbuf + i) = u;                 // fills hbuf parity-0 (uniform -> layout-free)
  if (blockIdx.x == 0 && threadIdx.x < 64)
    __hip_atomic_store(&flagh[threadIdx.x << 4], 1, __ATOMIC_RELAXED, __HIP_MEMORY_SCOPE_AGENT);
  if (blockIdx.x == 1 && threadIdx.x < 64)
    __hip_atomic_store(&flagr[threadIdx.x << 4], 0, __ATOMIC_RELAXED, __HIP_MEMORY_SCOPE_AGENT);
}

// --------------------------- precompute GEMM (256^2 tile) ------------------
// C[32768,3072] = A[32768,1024] @ B[3072,1024]^T   (bf16 in, fp32 acc)
__global__ void __launch_bounds__(512, 1) gemm_xw(const __hip_bfloat16* __restrict__ A,
                                                  const __hip_bfloat16* __restrict__ B,
                                                  __hip_bfloat16* __restrict__ C) {
  __shared__ __hip_bfloat16 As[256 * 64];   // 32 KB
  __shared__ __hip_bfloat16 Bs[256 * 64];   // 32 KB
  const int tid = threadIdx.x, lane = tid & 63, wv = tid >> 6;
  const int bn = blockIdx.x, bm = blockIdx.y;
  const int wm = wv >> 2, wn = wv & 3;
  const int n = lane & 15, q = lane >> 4;
  f32x4 acc[8][4];
#pragma unroll
  for (int i = 0; i < 8; ++i)
#pragma unroll
    for (int j = 0; j < 4; ++j) acc[i][j] = (f32x4){0.f, 0.f, 0.f, 0.f};
  const __hip_bfloat16* Ab = A + (size_t)bm * 256 * 1024;
  const __hip_bfloat16* Bb = B + (size_t)bn * 256 * 1024;
  for (int ko = 0; ko < 1024; ko += 64) {
#pragma unroll
    for (int r = 0; r < 4; ++r) {
      int chunk = r * 512 + wv * 64 + lane;   // 0..2047 16B-chunks
      int row = chunk >> 3, c16 = chunk & 7;  // 8 chunks per 128B row
      GL_LDS16(Ab + (size_t)row * 1024 + ko + c16 * 8, (char*)As + (r * 512 + wv * 64) * 16);
      GL_LDS16(Bb + (size_t)row * 1024 + ko + c16 * 8, (char*)Bs + (r * 512 + wv * 64) * 16);
    }
    __syncthreads();
#pragma unroll
    for (int ks = 0; ks < 2; ++ks) {
      bf16x8 af[8], bfr[4];
#pragma unroll
      for (int mi = 0; mi < 8; ++mi)
        af[mi] = ld16((const char*)As + (wm * 128 + mi * 16 + n) * 128 + ks * 64 + q * 16);
#pragma unroll
      for (int ni = 0; ni < 4; ++ni)
        bfr[ni] = ld16((const char*)Bs + (wn * 64 + ni * 16 + n) * 128 + ks * 64 + q * 16);
#pragma unroll
      for (int mi = 0; mi < 8; ++mi)
#pragma unroll
        for (int ni = 0; ni < 4; ++ni)
          acc[mi][ni] = mfma16(af[mi], bfr[ni], acc[mi][ni]);
    }
    __syncthreads();
  }
#pragma unroll
  for (int mi = 0; mi < 8; ++mi)
#pragma unroll
    for (int ni = 0; ni < 4; ++ni) {
      int col = bn * 256 + wn * 64 + ni * 16 + n;
#pragma unroll
      for (int r = 0; r < 4; ++r) {
        int row = bm * 256 + wm * 128 + mi * 16 + q * 4 + r;
        C[(size_t)row * 3072 + col] = __float2bfloat16(acc[mi][ni][r]);
      }
    }
}

// --------------------------- dataflow sync ---------------------------------
__device__ __forceinline__ void wait_flags(const int* flags, int target, int wv, int lane) {
  if (wv == 0) {
    const int* fp = flags + (lane << 4);   // one 64B line per WG flag
    while (!__all(__hip_atomic_load(fp, __ATOMIC_RELAXED, __HIP_MEMORY_SCOPE_AGENT) >= target))
      __builtin_amdgcn_s_sleep(1);
  }
  __syncthreads();
}
// R11(i): flag store from wave1 (tid==64) so wave0 (the poller) keeps an
// empty vmem queue. All waves drained their stores before the barrier, so
// any wave may publish the flag.
__device__ __forceinline__ void publish(int* p, int v) {
  asm volatile("s_waitcnt vmcnt(0)" ::: "memory");  // my chunk is at LLC
  __syncthreads();                                   // whole WG's chunk is
  if (threadIdx.x == 64)
    asm volatile("global_store_dword %0, %1, off sc0 sc1" :: "v"(p), "v"(v) : "memory");
}

// --------------------------- recurrent kernel (dataflow) -------------------
// 64 WGs x 256 thr. WG g owns h columns [16g, 16g+16).
// Exchange layout: byte = kb*1024 + row*16 + (col&7)*2,  kb = col>>3 (0..127).
__global__ void __launch_bounds__(256, 1) rec_k(
    const float* __restrict__ Wfc, const float* __restrict__ Wfc2,
    const __hip_bfloat16* __restrict__ xall,
    __hip_bfloat16* __restrict__ hbuf,    // 2 x 128 KiB (parity t&1)
    __hip_bfloat16* __restrict__ rhbuf,   // 2 x 128 KiB (parity t&1)
    float* __restrict__ out,
    int* __restrict__ flagh, int* __restrict__ flagr) {
  __shared__ __hip_bfloat16 W1s[32 * 1024];
  __shared__ __hip_bfloat16 W2s[16 * 1024];
  __shared__ char Pks[4 * 512];            // per-wave store-pack patch
  const int g = blockIdx.x, tid = threadIdx.x;
  const int lane = tid & 63, wv = tid >> 6;
  const int n = lane & 15, q = lane >> 4;
  const int gc = g * 16;

  {  // one-time weight load to LDS (swizzled: byte ^= (row&7)<<4)
    const int k0 = tid * 4;
    for (int j = 0; j < 32; ++j) {
      int grow = (j < 16) ? (gc + j) : (1024 + gc + (j - 16));
      float4 v = *(const float4*)(Wfc + (size_t)grow * 2048 + 1024 + k0);
      ushort4 u; u.x = f2bf(v.x); u.y = f2bf(v.y); u.z = f2bf(v.z); u.w = f2bf(v.w);
      *(ushort4*)((char*)W1s + j * 2048 + ((k0 * 2) ^ ((j & 7) << 4))) = u;
    }
    for (int j = 0; j < 16; ++j) {
      float4 v = *(const float4*)(Wfc2 + (size_t)(gc + j) * 2048 + 1024 + k0);
      ushort4 u; u.x = f2bf(v.x); u.y = f2bf(v.y); u.z = f2bf(v.z); u.w = f2bf(v.w);
      *(ushort4*)((char*)W2s + j * 2048 + ((k0 * 2) ^ ((j & 7) << 4))) = u;
    }
  }
  __syncthreads();

  const int m0 = wv * 16 + q * 4;        // C rows (batch) for this lane
  const int arow = wv * 16 + n;          // A-fragment row (batch)
  const int col = gc + n;                // h column this lane owns
  const char* w1z = (const char*)W1s + n * 2048;
  const char* w1r = (const char*)W1s + (16 + n) * 2048;
  const char* w2b = (const char*)W2s + n * 2048;
  const int sw = (n & 7) << 4;
  // gather base offset within a parity buffer (E layout)
  const int goff = q * 1024 + arow * 16;
  // store-pack addressing
  char* pk = Pks + wv * 512;
  const int wr_off = (n >> 3) * 256 + (n & 7) * 2;   // + (q*4+r)*16
  const int hi = lane >> 4 & 1;                      // for lane<32 readback
  const int r16 = lane & 15;
  const int st_off = (2 * g + hi) * 1024 + (wv * 16 + r16) * 16;

  float hf[4] = {1e-9f, 1e-9f, 1e-9f, 1e-9f};
  float xz[4], xrr[4], xc[4];
  {  // prefetch x(0)
    const __hip_bfloat16* xr = xall;
#pragma unroll
    for (int r = 0; r < 4; ++r) {
      xz[r]  = __bfloat162float(xr[(m0 + r) * 3072 + col]);
      xrr[r] = __bfloat162float(xr[(m0 + r) * 3072 + 1024 + col]);
      xc[r]  = __bfloat162float(xr[(m0 + r) * 3072 + 2048 + col]);
    }
  }

  for (int t = 0; t < TSTEPS; ++t) {
    // ================= phase 1: gates z,r ; publish r*h ====================
    wait_flags(flagh, t + 1, wv, lane);
    const char* hApt = (const char*)hbuf + (t & 1) * 131072 + goff;
    bf16x8 ha[32];
#pragma unroll
    for (int ks = 0; ks < 32; ++ks) ASM_LD16(ha[ks], hApt + ks * 4096);
    f32x4 az = (f32x4){0.f, 0.f, 0.f, 0.f}, ar = (f32x4){0.f, 0.f, 0.f, 0.f};
    WAITV(16);
#pragma unroll
    for (int ks = 0; ks < 16; ++ks) {
      az = mfma16(ha[ks], ld16(w1z + ((ks * 64 + q * 16) ^ sw)), az);
      ar = mfma16(ha[ks], ld16(w1r + ((ks * 64 + q * 16) ^ sw)), ar);
    }
    WAITV(0);
#pragma unroll
    for (int ks = 16; ks < 32; ++ks) {
      az = mfma16(ha[ks], ld16(w1z + ((ks * 64 + q * 16) ^ sw)), az);
      ar = mfma16(ha[ks], ld16(w1r + ((ks * 64 + q * 16) ^ sw)), ar);
    }
    float z4[4];
#pragma unroll
    for (int r = 0; r < 4; ++r) {
      z4[r] = sigm(az[r] + xz[r]);
      float rrh = sigm(ar[r] + xrr[r]) * hf[r];
      *(unsigned short*)(pk + wr_off + (q * 4 + r) * 16) = f2bf(rrh);
    }
    __syncthreads();  // pack patch complete per wave; cheap WG sync
    if (lane < 32) {
      i32x4 w = ldi4(pk + (lane >> 4) * 256 + r16 * 16);
      char* dst = (char*)rhbuf + (t & 1) * 131072 + st_off;
      ASM_ST16(dst, w);
    }
    publish(flagr + g * 16, t + 1);

    // ================= phase 2: candidate ; publish h ======================
    wait_flags(flagr, t + 1, wv, lane);
    const char* rApt = (const char*)rhbuf + (t & 1) * 131072 + goff;
#pragma unroll
    for (int ks = 0; ks < 32; ++ks) ASM_LD16(ha[ks], rApt + ks * 4096);
    f32x4 ac = (f32x4){0.f, 0.f, 0.f, 0.f};
    WAITV(16);
#pragma unroll
    for (int ks = 0; ks < 16; ++ks)
      ac = mfma16(ha[ks], ld16(w2b + ((ks * 64 + q * 16) ^ sw)), ac);
    WAITV(0);
#pragma unroll
    for (int ks = 16; ks < 32; ++ks)
      ac = mfma16(ha[ks], ld16(w2b + ((ks * 64 + q * 16) ^ sw)), ac);
#pragma unroll
    for (int r = 0; r < 4; ++r) {
      float th = tanh_fast(ac[r] + xc[r]);
      float hn = hf[r] + z4[r] * (th - hf[r]);
      hf[r] = hn;
      *(unsigned short*)(pk + wr_off + (q * 4 + r) * 16) = f2bf(hn);
    }
    __syncthreads();
    if (lane < 32) {
      i32x4 w = ldi4(pk + (lane >> 4) * 256 + r16 * 16);
      char* dst = (char*)hbuf + ((t + 1) & 1) * 131072 + st_off;
      ASM_ST16(dst, w);
    }
    publish(flagh + g * 16, t + 2);

    // ---- off critical path: out stores + x prefetch (overlap next wait) ----
#pragma unroll
    for (int r = 0; r < 4; ++r)
      out[((size_t)t * 64 + m0 + r) * 1024 + col] = hf[r];
    const int tn = (t + 1 < TSTEPS) ? t + 1 : t;
    const __hip_bfloat16* xr = xall + (size_t)tn * 64 * 3072;
#pragma unroll
    for (int r = 0; r < 4; ++r) {
      xz[r]  = __bfloat162float(xr[(m0 + r) * 3072 + col]);
      xrr[r] = __bfloat162float(xr[(m0 + r) * 3072 + 1024 + col]);
      xc[r]  = __bfloat162float(xr[(m0 + r) * 3072 + 2048 + col]);
    }
    // R11(ii): drain tail vmem so the next poll starts with vmcnt==0.
    // This wait overlaps other WGs' phase work (a full phase passes before
    // the next flag can be set), so it costs nothing on the critical path.
    WAITV(0);
  }
}

// --------------------------- host launch -----------------------------------
extern "C" void kernel_launch(void* const* d_in, const int* in_sizes, int n_in,
                              void* d_out, int out_size, void* d_ws, size_t ws_size,
                              hipStream_t stream) {
  if (ws_size < WS_NEED) return;
  const float* x    = (const float*)d_in[0];
  const float* Wfc  = (const float*)d_in[1];
  const float* Wfc2 = (const float*)d_in[2];
  float* out = (float*)d_out;
  char* ws = (char*)d_ws;

  __hip_bfloat16* xall  = (__hip_bfloat16*)(ws + XALL_OFF);
  __hip_bfloat16* Wxp   = (__hip_bfloat16*)(ws + WXP_OFF);
  __hip_bfloat16* hbuf  = (__hip_bfloat16*)(ws + HBUF_OFF);
  __hip_bfloat16* rhbuf = (__hip_bfloat16*)(ws + RHBUF_OFF);
  int* flagh            = (int*)(ws + FLAG_OFF);
  int* flagr            = (int*)(ws + FLAG_OFF + 4096);
  __hip_bfloat16* Xbf   = (__hip_bfloat16*)d_out;  // dead storage until rec_k

  cvt_x<<<32768, 256, 0, stream>>>(x, Xbf);
  pack_w<<<3072, 256, 0, stream>>>(Wfc, Wfc2, Wxp);
  init_k<<<64, 256, 0, stream>>>(hbuf, flagh, flagr);
  gemm_xw<<<dim3(12, 128), 512, 0, stream>>>(Xbf, Wxp, xall);

  void* args[] = {(void*)&Wfc, (void*)&Wfc2, (void*)&xall, (void*)&hbuf,
                  (void*)&rhbuf, (void*)&out, (void*)&flagh, (void*)&flagr};
  (void)hipLaunchCooperativeKernel((void*)rec_k, dim3(NWG), dim3(256), args, 0, stream);
}

// Round 12
// 3920.719 us; speedup vs baseline: 1.0127x; 1.0127x over previous
//
#include <hip/hip_runtime.h>
#include <hip/hip_bf16.h>
#include <stdint.h>

// ---------------------------------------------------------------------------
// ConvLSTM (GRU-style) T=512 B=64 D=1024 H=1024.  FINAL (R10 state).
// xall = X @ [Wzx;Wrx;Wcx]^T (parallel 256^2-tile GEMM, bf16), then
// cooperative DATAFLOW recurrent kernel: 64 WGs x 16 cols, per-WG monotone
// flags, double-buffered h/rh in MFMA-fragment-major layout
//   E[kb = col/8][row 0..63][8 bf16]   (16B per (kb,row))
// Structure is latency-bound: 1024 dependent LLC all-to-all exchanges at
// ~3.5us each (drain + flag + detect + gather). HBM 4.4%, MfmaUtil 2.3% --
// the floor is the exchange chain, not a BW/compute roofline.
// ---------------------------------------------------------------------------

typedef float  f32x4  __attribute__((ext_vector_type(4)));
typedef int    i32x4  __attribute__((ext_vector_type(4)));
typedef __bf16 bf16x8 __attribute__((ext_vector_type(8)));

#define NWG 64
#define TSTEPS 512

// ws layout (bytes)
#define XALL_OFF 0UL
#define XALL_BYTES (32768UL * 3072UL * 2UL)            // 201326592
#define WXP_OFF   (XALL_OFF + XALL_BYTES)
#define WXP_BYTES (3072UL * 1024UL * 2UL)              // 6291456
#define HBUF_OFF  (WXP_OFF + WXP_BYTES)                // 2 x 131072
#define RHBUF_OFF (HBUF_OFF + 262144UL)                // 2 x 131072
#define FLAG_OFF  (RHBUF_OFF + 262144UL)               // flagh 4KB, flagr 4KB
#define WS_NEED   (FLAG_OFF + 8192UL)

#define GL_LDS16(g, l) __builtin_amdgcn_global_load_lds( \
    (const __attribute__((address_space(1))) void*)(const void*)(g), \
    (__attribute__((address_space(3))) void*)(void*)(l), 16, 0, 0)

// coherent 16B load / store (bypass stale L1/L2, coalescable at LLC)
#define ASM_LD16(dst, p) \
  asm volatile("global_load_dwordx4 %0, %1, off sc0 sc1" \
               : "=&v"(dst) : "v"(p) : "memory")
#define ASM_ST16(p, v) \
  asm volatile("global_store_dwordx4 %0, %1, off sc0 sc1" \
               :: "v"(p), "v"(v) : "memory")
#define WAITV(N) do { asm volatile("s_waitcnt vmcnt(" #N ")" ::: "memory"); \
                      __builtin_amdgcn_sched_barrier(0); } while (0)

__device__ __forceinline__ unsigned short f2bf(float f) {
  __hip_bfloat16 h = __float2bfloat16(f);
  return __builtin_bit_cast(unsigned short, h);
}
__device__ __forceinline__ bf16x8 ld16(const void* p) {
  return __builtin_bit_cast(bf16x8, *(const uint4*)p);
}
__device__ __forceinline__ i32x4 ldi4(const void* p) {
  return __builtin_bit_cast(i32x4, *(const uint4*)p);
}
__device__ __forceinline__ f32x4 mfma16(bf16x8 a, bf16x8 b, f32x4 c) {
  return __builtin_amdgcn_mfma_f32_16x16x32_bf16(a, b, c, 0, 0, 0);
}
__device__ __forceinline__ float sigm(float x) {
  return __builtin_amdgcn_rcpf(1.0f + __builtin_amdgcn_exp2f(-1.4426950408889634f * x));
}
__device__ __forceinline__ float tanh_fast(float x) {
  return 1.0f - 2.0f * __builtin_amdgcn_rcpf(1.0f + __builtin_amdgcn_exp2f(2.8853900817779268f * x));
}

// --------------------------- prep kernels ----------------------------------
__global__ void cvt_x(const float* __restrict__ x, __hip_bfloat16* __restrict__ o) {
  size_t i = ((size_t)blockIdx.x * 256 + threadIdx.x) * 4;
  float4 v = *(const float4*)(x + i);
  ushort4 u; u.x = f2bf(v.x); u.y = f2bf(v.y); u.z = f2bf(v.z); u.w = f2bf(v.w);
  *(ushort4*)(o + i) = u;
}

__global__ void pack_w(const float* __restrict__ Wfc, const float* __restrict__ Wfc2,
                       __hip_bfloat16* __restrict__ Wxp) {
  int row = blockIdx.x;
  int k = threadIdx.x * 4;
  const float* src = (row < 2048) ? (Wfc + (size_t)row * 2048 + k)
                                  : (Wfc2 + (size_t)(row - 2048) * 2048 + k);
  float4 v = *(const float4*)src;
  ushort4 u; u.x = f2bf(v.x); u.y = f2bf(v.y); u.z = f2bf(v.z); u.w = f2bf(v.w);
  *(ushort4*)(Wxp + (size_t)row * 1024 + k) = u;
}

__global__ void init_k(__hip_bfloat16* __restrict__ hbuf,
                       int* __restrict__ flagh, int* __restrict__ flagr) {
  size_t i = ((size_t)blockIdx.x * 256 + threadIdx.x) * 4;
  unsigned short hv = f2bf(1e-9f);
  ushort4 u; u.x = hv; u.y = hv; u.z = hv; u.w = hv;
  *(ushort4*)(hbuf + i) = u;                 // fills hbuf parity-0 (uniform -> layout-free)
  if (blockIdx.x == 0 && threadIdx.x < 64)
    __hip_atomic_store(&flagh[threadIdx.x << 4], 1, __ATOMIC_RELAXED, __HIP_MEMORY_SCOPE_AGENT);
  if (blockIdx.x == 1 && threadIdx.x < 64)
    __hip_atomic_store(&flagr[threadIdx.x << 4], 0, __ATOMIC_RELAXED, __HIP_MEMORY_SCOPE_AGENT);
}

// --------------------------- precompute GEMM (256^2 tile) ------------------
// C[32768,3072] = A[32768,1024] @ B[3072,1024]^T   (bf16 in, fp32 acc)
// 512 threads = 8 waves (2 wm x 4 wn); per-wave output 128x64.
__global__ void __launch_bounds__(512, 1) gemm_xw(const __hip_bfloat16* __restrict__ A,
                                                  const __hip_bfloat16* __restrict__ B,
                                                  __hip_bfloat16* __restrict__ C) {
  __shared__ __hip_bfloat16 As[256 * 64];   // 32 KB
  __shared__ __hip_bfloat16 Bs[256 * 64];   // 32 KB
  const int tid = threadIdx.x, lane = tid & 63, wv = tid >> 6;
  const int bn = blockIdx.x, bm = blockIdx.y;
  const int wm = wv >> 2, wn = wv & 3;
  const int n = lane & 15, q = lane >> 4;
  f32x4 acc[8][4];
#pragma unroll
  for (int i = 0; i < 8; ++i)
#pragma unroll
    for (int j = 0; j < 4; ++j) acc[i][j] = (f32x4){0.f, 0.f, 0.f, 0.f};
  const __hip_bfloat16* Ab = A + (size_t)bm * 256 * 1024;
  const __hip_bfloat16* Bb = B + (size_t)bn * 256 * 1024;
  for (int ko = 0; ko < 1024; ko += 64) {
#pragma unroll
    for (int r = 0; r < 4; ++r) {
      int chunk = r * 512 + wv * 64 + lane;   // 0..2047 16B-chunks
      int row = chunk >> 3, c16 = chunk & 7;  // 8 chunks per 128B row
      GL_LDS16(Ab + (size_t)row * 1024 + ko + c16 * 8, (char*)As + (r * 512 + wv * 64) * 16);
      GL_LDS16(Bb + (size_t)row * 1024 + ko + c16 * 8, (char*)Bs + (r * 512 + wv * 64) * 16);
    }
    __syncthreads();
#pragma unroll
    for (int ks = 0; ks < 2; ++ks) {
      bf16x8 af[8], bfr[4];
#pragma unroll
      for (int mi = 0; mi < 8; ++mi)
        af[mi] = ld16((const char*)As + (wm * 128 + mi * 16 + n) * 128 + ks * 64 + q * 16);
#pragma unroll
      for (int ni = 0; ni < 4; ++ni)
        bfr[ni] = ld16((const char*)Bs + (wn * 64 + ni * 16 + n) * 128 + ks * 64 + q * 16);
#pragma unroll
      for (int mi = 0; mi < 8; ++mi)
#pragma unroll
        for (int ni = 0; ni < 4; ++ni)
          acc[mi][ni] = mfma16(af[mi], bfr[ni], acc[mi][ni]);
    }
    __syncthreads();
  }
#pragma unroll
  for (int mi = 0; mi < 8; ++mi)
#pragma unroll
    for (int ni = 0; ni < 4; ++ni) {
      int col = bn * 256 + wn * 64 + ni * 16 + n;
#pragma unroll
      for (int r = 0; r < 4; ++r) {
        int row = bm * 256 + wm * 128 + mi * 16 + q * 4 + r;
        C[(size_t)row * 3072 + col] = __float2bfloat16(acc[mi][ni][r]);
      }
    }
}

// --------------------------- dataflow sync ---------------------------------
__device__ __forceinline__ void wait_flags(const int* flags, int target, int wv, int lane) {
  if (wv == 0) {
    const int* fp = flags + (lane << 4);   // one 64B line per WG flag
    while (!__all(__hip_atomic_load(fp, __ATOMIC_RELAXED, __HIP_MEMORY_SCOPE_AGENT) >= target))
      __builtin_amdgcn_s_sleep(1);
  }
  __syncthreads();
}
__device__ __forceinline__ void publish(int* p, int v) {
  asm volatile("s_waitcnt vmcnt(0)" ::: "memory");  // my chunk is at LLC
  __syncthreads();                                   // whole WG's chunk is
  if (threadIdx.x == 0)
    asm volatile("global_store_dword %0, %1, off sc0 sc1" :: "v"(p), "v"(v) : "memory");
}

// --------------------------- recurrent kernel (dataflow) -------------------
// 64 WGs x 256 thr. WG g owns h columns [16g, 16g+16).
// Exchange layout: byte = kb*1024 + row*16 + (col&7)*2,  kb = col>>3 (0..127).
__global__ void __launch_bounds__(256, 1) rec_k(
    const float* __restrict__ Wfc, const float* __restrict__ Wfc2,
    const __hip_bfloat16* __restrict__ xall,
    __hip_bfloat16* __restrict__ hbuf,    // 2 x 128 KiB (parity t&1)
    __hip_bfloat16* __restrict__ rhbuf,   // 2 x 128 KiB (parity t&1)
    float* __restrict__ out,
    int* __restrict__ flagh, int* __restrict__ flagr) {
  __shared__ __hip_bfloat16 W1s[32 * 1024];
  __shared__ __hip_bfloat16 W2s[16 * 1024];
  __shared__ char Pks[4 * 512];            // per-wave store-pack patch
  const int g = blockIdx.x, tid = threadIdx.x;
  const int lane = tid & 63, wv = tid >> 6;
  const int n = lane & 15, q = lane >> 4;
  const int gc = g * 16;

  {  // one-time weight load to LDS (swizzled: byte ^= (row&7)<<4)
    const int k0 = tid * 4;
    for (int j = 0; j < 32; ++j) {
      int grow = (j < 16) ? (gc + j) : (1024 + gc + (j - 16));
      float4 v = *(const float4*)(Wfc + (size_t)grow * 2048 + 1024 + k0);
      ushort4 u; u.x = f2bf(v.x); u.y = f2bf(v.y); u.z = f2bf(v.z); u.w = f2bf(v.w);
      *(ushort4*)((char*)W1s + j * 2048 + ((k0 * 2) ^ ((j & 7) << 4))) = u;
    }
    for (int j = 0; j < 16; ++j) {
      float4 v = *(const float4*)(Wfc2 + (size_t)(gc + j) * 2048 + 1024 + k0);
      ushort4 u; u.x = f2bf(v.x); u.y = f2bf(v.y); u.z = f2bf(v.z); u.w = f2bf(v.w);
      *(ushort4*)((char*)W2s + j * 2048 + ((k0 * 2) ^ ((j & 7) << 4))) = u;
    }
  }
  __syncthreads();

  const int m0 = wv * 16 + q * 4;        // C rows (batch) for this lane
  const int arow = wv * 16 + n;          // A-fragment row (batch)
  const int col = gc + n;                // h column this lane owns
  const char* w1z = (const char*)W1s + n * 2048;
  const char* w1r = (const char*)W1s + (16 + n) * 2048;
  const char* w2b = (const char*)W2s + n * 2048;
  const int sw = (n & 7) << 4;
  // gather base offset within a parity buffer (E layout)
  const int goff = q * 1024 + arow * 16;
  // store-pack addressing
  char* pk = Pks + wv * 512;
  const int wr_off = (n >> 3) * 256 + (n & 7) * 2;   // + (q*4+r)*16
  const int hi = lane >> 4 & 1;                      // for lane<32 readback
  const int r16 = lane & 15;
  const int st_off = (2 * g + hi) * 1024 + (wv * 16 + r16) * 16;

  float hf[4] = {1e-9f, 1e-9f, 1e-9f, 1e-9f};
  float xz[4], xrr[4], xc[4];
  {  // prefetch x(0)
    const __hip_bfloat16* xr = xall;
#pragma unroll
    for (int r = 0; r < 4; ++r) {
      xz[r]  = __bfloat162float(xr[(m0 + r) * 3072 + col]);
      xrr[r] = __bfloat162float(xr[(m0 + r) * 3072 + 1024 + col]);
      xc[r]  = __bfloat162float(xr[(m0 + r) * 3072 + 2048 + col]);
    }
  }

  for (int t = 0; t < TSTEPS; ++t) {
    // ================= phase 1: gates z,r ; publish r*h ====================
    wait_flags(flagh, t + 1, wv, lane);
    const char* hApt = (const char*)hbuf + (t & 1) * 131072 + goff;
    bf16x8 ha[32];
#pragma unroll
    for (int ks = 0; ks < 32; ++ks) ASM_LD16(ha[ks], hApt + ks * 4096);
    f32x4 az = (f32x4){0.f, 0.f, 0.f, 0.f}, ar = (f32x4){0.f, 0.f, 0.f, 0.f};
    WAITV(16);
#pragma unroll
    for (int ks = 0; ks < 16; ++ks) {
      az = mfma16(ha[ks], ld16(w1z + ((ks * 64 + q * 16) ^ sw)), az);
      ar = mfma16(ha[ks], ld16(w1r + ((ks * 64 + q * 16) ^ sw)), ar);
    }
    WAITV(0);
#pragma unroll
    for (int ks = 16; ks < 32; ++ks) {
      az = mfma16(ha[ks], ld16(w1z + ((ks * 64 + q * 16) ^ sw)), az);
      ar = mfma16(ha[ks], ld16(w1r + ((ks * 64 + q * 16) ^ sw)), ar);
    }
    float z4[4];
#pragma unroll
    for (int r = 0; r < 4; ++r) {
      z4[r] = sigm(az[r] + xz[r]);
      float rrh = sigm(ar[r] + xrr[r]) * hf[r];
      *(unsigned short*)(pk + wr_off + (q * 4 + r) * 16) = f2bf(rrh);
    }
    __syncthreads();  // pack patch complete per wave; cheap WG sync
    if (lane < 32) {
      i32x4 w = ldi4(pk + (lane >> 4) * 256 + r16 * 16);
      char* dst = (char*)rhbuf + (t & 1) * 131072 + st_off;
      ASM_ST16(dst, w);
    }
    publish(flagr + g * 16, t + 1);

    // ================= phase 2: candidate ; publish h ======================
    wait_flags(flagr, t + 1, wv, lane);
    const char* rApt = (const char*)rhbuf + (t & 1) * 131072 + goff;
#pragma unroll
    for (int ks = 0; ks < 32; ++ks) ASM_LD16(ha[ks], rApt + ks * 4096);
    f32x4 ac = (f32x4){0.f, 0.f, 0.f, 0.f};
    WAITV(16);
#pragma unroll
    for (int ks = 0; ks < 16; ++ks)
      ac = mfma16(ha[ks], ld16(w2b + ((ks * 64 + q * 16) ^ sw)), ac);
    WAITV(0);
#pragma unroll
    for (int ks = 16; ks < 32; ++ks)
      ac = mfma16(ha[ks], ld16(w2b + ((ks * 64 + q * 16) ^ sw)), ac);
#pragma unroll
    for (int r = 0; r < 4; ++r) {
      float th = tanh_fast(ac[r] + xc[r]);
      float hn = hf[r] + z4[r] * (th - hf[r]);
      hf[r] = hn;
      *(unsigned short*)(pk + wr_off + (q * 4 + r) * 16) = f2bf(hn);
    }
    __syncthreads();
    if (lane < 32) {
      i32x4 w = ldi4(pk + (lane >> 4) * 256 + r16 * 16);
      char* dst = (char*)hbuf + ((t + 1) & 1) * 131072 + st_off;
      ASM_ST16(dst, w);
    }
    publish(flagh + g * 16, t + 2);

    // ---- off critical path: out stores + x prefetch (overlap next wait) ----
#pragma unroll
    for (int r = 0; r < 4; ++r)
      out[((size_t)t * 64 + m0 + r) * 1024 + col] = hf[r];
    const int tn = (t + 1 < TSTEPS) ? t + 1 : t;
    const __hip_bfloat16* xr = xall + (size_t)tn * 64 * 3072;
#pragma unroll
    for (int r = 0; r < 4; ++r) {
      xz[r]  = __bfloat162float(xr[(m0 + r) * 3072 + col]);
      xrr[r] = __bfloat162float(xr[(m0 + r) * 3072 + 1024 + col]);
      xc[r]  = __bfloat162float(xr[(m0 + r) * 3072 + 2048 + col]);
    }
  }
}

// --------------------------- host launch -----------------------------------
extern "C" void kernel_launch(void* const* d_in, const int* in_sizes, int n_in,
                              void* d_out, int out_size, void* d_ws, size_t ws_size,
                              hipStream_t stream) {
  if (ws_size < WS_NEED) return;
  const float* x    = (const float*)d_in[0];
  const float* Wfc  = (const float*)d_in[1];
  const float* Wfc2 = (const float*)d_in[2];
  float* out = (float*)d_out;
  char* ws = (char*)d_ws;

  __hip_bfloat16* xall  = (__hip_bfloat16*)(ws + XALL_OFF);
  __hip_bfloat16* Wxp   = (__hip_bfloat16*)(ws + WXP_OFF);
  __hip_bfloat16* hbuf  = (__hip_bfloat16*)(ws + HBUF_OFF);
  __hip_bfloat16* rhbuf = (__hip_bfloat16*)(ws + RHBUF_OFF);
  int* flagh            = (int*)(ws + FLAG_OFF);
  int* flagr            = (int*)(ws + FLAG_OFF + 4096);
  __hip_bfloat16* Xbf   = (__hip_bfloat16*)d_out;  // dead storage until rec_k

  cvt_x<<<32768, 256, 0, stream>>>(x, Xbf);
  pack_w<<<3072, 256, 0, stream>>>(Wfc, Wfc2, Wxp);
  init_k<<<64, 256, 0, stream>>>(hbuf, flagh, flagr);
  gemm_xw<<<dim3(12, 128), 512, 0, stream>>>(Xbf, Wxp, xall);

  void* args[] = {(void*)&Wfc, (void*)&Wfc2, (void*)&xall, (void*)&hbuf,
                  (void*)&rhbuf, (void*)&out, (void*)&flagh, (void*)&flagr};
  (void)hipLaunchCooperativeKernel((void*)rec_k, dim3(NWG), dim3(256), args, 0, stream);
}